// Round 4
// baseline (11078.197 us; speedup 1.0000x reference)
//
#include <hip/hip_runtime.h>
#include <stdint.h>

typedef __attribute__((ext_vector_type(4))) float f32x4;
typedef __attribute__((ext_vector_type(2))) unsigned int u32x2;
typedef unsigned long long u64;

#define T_STEPS 4096
#define HID 1024
#define NBLK 256

static __device__ __forceinline__ float u2f(unsigned int u) {
    union { float f; unsigned int i; } c; c.i = u; return c.f;
}
static __device__ __forceinline__ unsigned int f2u(float f) {
    union { float f; unsigned int i; } c; c.f = f; return c.i;
}

// ---------------------------------------------------------------------------
// Fully fused persistent LSTM, fp32. 256 blocks x 256 threads, 1 block/CU.
// Block b owns hidden units [4b,4b+4) -> 16 gate columns
//   col(c) = (c>>2)*1024 + b*4 + (c&3), c = tid&15.
// Thread (c, s=tid>>4) holds U/W[64s..64s+64)[col] in VGPRs.
//
// SINGLE-HOP mailbox: each h value is published as an 8-byte pair
// {f32 h, u32 tag=t+1} with ONE global_store_dwordx2 sc0 sc1 (8 B aligned
// => single-copy atomic). Readers poll the pairs; tag arrival == data arrival.
//
// R4 vs the 10.75 ms R0 baseline — ONE change, made SOUND this time:
//  * Depth-1 pipelined poll via compiler-managed RELAXED AGENT-SCOPE ATOMIC
//    LOADS (__hip_atomic_load). R1/R3 proved split-asm pipelining corrupts
//    data: CDNA has no VGPR scoreboard for VMEM; separate asm blocks let
//    the compiler insert v_mov copies of the destination regs BEFORE any
//    waitcnt. Atomic loads keep the async-destination tracking inside the
//    compiler, which places s_waitcnt before first USE (after W.x) while
//    issuing the loads early. Atomics also can't be CSE'd, so the retry
//    loop re-loads every iteration.
//  * Issue point: after a 4-iteration warm-up chunk of W.x (~100 cy past
//    S1), matching when publishes (gates ~100cy + store flight) become
//    visible — R2 showed sampling EARLIER than that forces retries.
// Everything else identical to R0: S2 kept, sc0 sc1 publish asm kept,
// single red[64], rotating-writer out rows.
//
// Parity-2 slot safety: block b overwrites pair[p][j] (h_t -> h_{t+2}) at
// step t+2 only after its poll of ALL h_{t+1} tags succeeded; any block
// publishes h_{t+1} only after ITS loads of h_t completed (data dependency).
// Tags monotonic per slot; poll uses >=. Workspace: pair[2][1024] u64 (16 KB).
// ---------------------------------------------------------------------------
__global__ __launch_bounds__(256, 1) void lstm_fused(
    const float* __restrict__ x,    // [4096,1024]
    const float* __restrict__ W,    // [1024,4096]
    const float* __restrict__ U,    // [1024,4096]
    const float* __restrict__ bias, // [4096]
    float* __restrict__ out,        // [4096*1024 + 1024 + 1024]
    u64* __restrict__ pairs)        // [2][1024] {f32 h, u32 tag}, zeroed
{
    const int tid  = threadIdx.x;
    const int b    = blockIdx.x;
    const int c    = tid & 15;
    const int s    = tid >> 4;
    const int col  = (c >> 2) * 1024 + b * 4 + (c & 3);
    const int lane = tid & 63;
    const int wave = tid >> 6;

    __shared__ __align__(16) float h_lds[16 * 68];     // h[k] at (k>>6)*68+(k&63)
    __shared__ __align__(16) float x_lds[2][16 * 68];
    __shared__ __align__(16) float red[64];
    __shared__ __align__(16) float bias_l[16];

    float Ureg[64], Wreg[64];
    #pragma unroll
    for (int i = 0; i < 64; ++i) {
        const size_t r = (size_t)(s * 64 + i) * 4096 + col;
        Ureg[i] = U[r];
        Wreg[i] = W[r];
    }
    if (tid < 16) bias_l[tid] = bias[col];

    for (int i = tid; i < 16 * 68; i += 256) h_lds[i] = 0.0f;   // h0 = 0
    const int xofs = (tid >> 4) * 68 + (tid & 15) * 4;
    *(f32x4*)&x_lds[0][xofs] = *(const f32x4*)(x + (size_t)tid * 4);
    f32x4 xpre = *(const f32x4*)(x + 1024 + (size_t)tid * 4);
    __syncthreads();

    const int hbase = s * 68;
    const int hofs  = ((tid * 4) >> 6) * 68 + ((tid * 4) & 63);  // stage slot

    // prologue: W.x_0 partial (4 independent FMA chains)
    float acc_x;
    {
        float b0 = 0.f, b1 = 0.f, b2 = 0.f, b3 = 0.f;
        #pragma unroll
        for (int i = 0; i < 16; ++i) {
            f32x4 x4 = *(const f32x4*)&x_lds[0][hbase + 4 * i];
            b0 += x4.x * Wreg[4*i];   b1 += x4.y * Wreg[4*i+1];
            b2 += x4.z * Wreg[4*i+2]; b3 += x4.w * Wreg[4*i+3];
        }
        acc_x = (b0 + b1) + (b2 + b3);
    }

    float c_reg = 0.0f;   // cell state: wave-0 lane u tracks unit b*4+(u&3)

    for (int t = 0; t < T_STEPS; ++t) {
        const int p   = t & 1;
        const int nxt = (t + 1) & 1;

        // 1: acc = W.x_t (precomputed) + U.h_{t-1}
        float acc;
        {
            float a0 = 0.f, a1 = 0.f, a2 = 0.f, a3 = 0.f;
            #pragma unroll
            for (int i = 0; i < 16; ++i) {
                f32x4 h4 = *(const f32x4*)&h_lds[hbase + 4 * i];
                a0 += h4.x * Ureg[4*i];   a1 += h4.y * Ureg[4*i+1];
                a2 += h4.z * Ureg[4*i+2]; a3 += h4.w * Ureg[4*i+3];
            }
            acc = acc_x + ((a0 + a1) + (a2 + a3));
        }
        // 2: lanes {c, c+16, c+32, c+48} share a column
        acc += __shfl_down(acc, 32);
        acc += __shfl_down(acc, 16);
        if (lane < 16) red[wave * 16 + lane] = acc;

        // rotate x double-buffer: write x_{t+1}, prefetch x_{t+2}
        *(f32x4*)&x_lds[nxt][xofs] = xpre;
        {
            const int tp2 = (t + 2 < T_STEPS) ? (t + 2) : (T_STEPS - 1);
            xpre = *(const f32x4*)(x + (size_t)tp2 * 1024 + tid * 4);
        }
        __syncthreads();   // [S1] red + x_lds[nxt] visible

        // 3: wave 0 — gates; lanes 0-3 publish {h, t+1} pairs (one store each)
        if (wave == 0) {
            const int cc = lane & 15;
            const float gv = red[cc] + red[16 + cc] + red[32 + cc] + red[48 + cc]
                           + bias_l[cc];
            const int u = lane & 3;
            const float gi = __shfl(gv, u);
            const float gf = __shfl(gv, 4 + u);
            const float gg = __shfl(gv, 8 + u);
            const float go = __shfl(gv, 12 + u);
            const float iv = 1.0f / (1.0f + __expf(-gi));
            const float fv = 1.0f / (1.0f + __expf(-gf));
            const float tg = 1.0f - 2.0f / (1.0f + __expf(2.0f * gg));
            const float ov = 1.0f / (1.0f + __expf(-go));
            const float cn = fv * c_reg + iv * tg;
            c_reg = cn;
            const float hn = ov * (1.0f - 2.0f / (1.0f + __expf(2.0f * cn)));
            if (t == T_STEPS - 1) {
                if (lane < 4) {
                    out[(size_t)t * HID + b * 4 + lane] = hn;               // row 4095
                    out[(size_t)T_STEPS * HID + b * 4 + lane] = hn;         // h_T
                    out[(size_t)T_STEPS * HID + HID + b * 4 + lane] = cn;   // c_T
                }
            } else if (lane < 4) {
                u32x2 pr;
                pr.x = f2u(hn);
                pr.y = (unsigned int)(t + 1);
                u64* pp = pairs + (size_t)p * 1024 + b * 4 + lane;
                asm volatile("global_store_dwordx2 %0, %1, off sc0 sc1"
                             :: "v"(pp), "v"(pr) : "memory");
            }
        }
        if (t == T_STEPS - 1) break;

        const unsigned int want = (unsigned int)(t + 1);
        const u64* pp = pairs + (size_t)p * 1024 + tid * 4;

        // 4a: W.x_{t+1} warm-up chunk (~100 cy) — lets the publishes get
        //     into flight before the first poll sample is issued.
        float b0 = 0.f, b1 = 0.f, b2 = 0.f, b3 = 0.f;
        #pragma unroll
        for (int i = 0; i < 4; ++i) {
            f32x4 x4 = *(const f32x4*)&x_lds[nxt][hbase + 4 * i];
            b0 += x4.x * Wreg[4*i];   b1 += x4.y * Wreg[4*i+1];
            b2 += x4.z * Wreg[4*i+2]; b3 += x4.w * Wreg[4*i+3];
        }

        // 4b: ISSUE first poll round (compiler-managed async loads; the
        //     s_waitcnt lands before first use, after the rest of W.x).
        u64 a0 = __hip_atomic_load(pp + 0, __ATOMIC_RELAXED, __HIP_MEMORY_SCOPE_AGENT);
        u64 a1 = __hip_atomic_load(pp + 1, __ATOMIC_RELAXED, __HIP_MEMORY_SCOPE_AGENT);
        u64 a2 = __hip_atomic_load(pp + 2, __ATOMIC_RELAXED, __HIP_MEMORY_SCOPE_AGENT);
        u64 a3 = __hip_atomic_load(pp + 3, __ATOMIC_RELAXED, __HIP_MEMORY_SCOPE_AGENT);

        // 4c: rest of W.x_{t+1} (overlaps the poll flight)
        #pragma unroll
        for (int i = 4; i < 16; ++i) {
            f32x4 x4 = *(const f32x4*)&x_lds[nxt][hbase + 4 * i];
            b0 += x4.x * Wreg[4*i];   b1 += x4.y * Wreg[4*i+1];
            b2 += x4.z * Wreg[4*i+2]; b3 += x4.w * Wreg[4*i+3];
        }
        acc_x = (b0 + b1) + (b2 + b3);

        // 5: check; on failure re-load (atomics are re-performed each iter)
        while (!((unsigned int)(a0 >> 32) >= want &&
                 (unsigned int)(a1 >> 32) >= want &&
                 (unsigned int)(a2 >> 32) >= want &&
                 (unsigned int)(a3 >> 32) >= want)) {
            a0 = __hip_atomic_load(pp + 0, __ATOMIC_RELAXED, __HIP_MEMORY_SCOPE_AGENT);
            a1 = __hip_atomic_load(pp + 1, __ATOMIC_RELAXED, __HIP_MEMORY_SCOPE_AGENT);
            a2 = __hip_atomic_load(pp + 2, __ATOMIC_RELAXED, __HIP_MEMORY_SCOPE_AGENT);
            a3 = __hip_atomic_load(pp + 3, __ATOMIC_RELAXED, __HIP_MEMORY_SCOPE_AGENT);
        }
        {
            f32x4 hv4;
            hv4.x = u2f((unsigned int)a0);
            hv4.y = u2f((unsigned int)a1);
            hv4.z = u2f((unsigned int)a2);
            hv4.w = u2f((unsigned int)a3);
            // rotating writer: block (t & 255) emits the full coalesced row t
            if (b == (t & 255))
                *(f32x4*)(out + (size_t)t * HID + tid * 4) = hv4;
            *(f32x4*)&h_lds[hofs] = hv4;   // stage h_t
        }
        __syncthreads();   // [S2] h_t staged
    }
}

extern "C" void kernel_launch(void* const* d_in, const int* in_sizes, int n_in,
                              void* d_out, int out_size, void* d_ws, size_t ws_size,
                              hipStream_t stream) {
    const float* x    = (const float*)d_in[0];
    const float* W    = (const float*)d_in[1];
    const float* U    = (const float*)d_in[2];
    const float* bias = (const float*)d_in[3];
    float* out = (float*)d_out;

    // Workspace: pairs[2][1024] x 8 B = 16 KB @ +0 (zeroed: tag fields must
    // start below 1; re-poisoned 0xAA would read as huge tags).
    u64* pairs = (u64*)d_ws;

    hipMemsetAsync(pairs, 0, 2 * 1024 * sizeof(u64), stream);
    lstm_fused<<<NBLK, 256, 0, stream>>>(x, W, U, bias, out, pairs);
}

// Round 5
// 9450.172 us; speedup vs baseline: 1.1723x; 1.1723x over previous
//
#include <hip/hip_runtime.h>
#include <stdint.h>

typedef __attribute__((ext_vector_type(4))) float f32x4;
typedef __attribute__((ext_vector_type(2))) unsigned int u32x2;
typedef __attribute__((ext_vector_type(4))) unsigned int u32x4;

#define T_STEPS 4096
#define HID 1024
#define NBLK 256
#define NREP 8          // mailbox replicas (fan-in 256 -> 32 readers/line)

static __device__ __forceinline__ float u2f(unsigned int u) {
    union { float f; unsigned int i; } c; c.i = u; return c.f;
}
static __device__ __forceinline__ unsigned int f2u(float f) {
    union { float f; unsigned int i; } c; c.f = f; return c.i;
}

// ---------------------------------------------------------------------------
// Fully fused persistent LSTM, fp32. 256 blocks x 256 threads, 1 block/CU.
// Block b owns hidden units [4b,4b+4) -> 16 gate columns
//   col(c) = (c>>2)*1024 + b*4 + (c&3), c = tid&15.
// Thread (c, s=tid>>4) holds U/W[64s..64s+64)[col] in VGPRs.
//
// SINGLE-HOP mailbox, 8x REPLICATED. Each h value is an 8-byte pair
// {f32 h, u32 tag=t+1}, stored with ONE global_store_dwordx2 sc0 sc1
// (8 B aligned => single-copy atomic; tag arrival == data arrival).
//
// R5 vs the 10.75 ms R0 baseline — ONE change:
//  * Mailbox replicated 8x: pairs[8][2][1024]. Publisher wave0 already
//    computes hn redundantly on all 64 lanes; lanes 0-31 now store, lane l
//    writing unit b*4+(l&3) into replica l>>2 — SAME single store
//    instruction, wider exec mask, zero publisher-path cycles added.
//    Readers poll replica (bid & 7) only.
//    Rationale: R2/R4 showed extra poll rounds SLOW the system (+3% each)
//    => detection is fan-in-congestion-bound, not latency-bound. Every
//    mailbox line was read by all 256 blocks per round (>=256 cy service
//    per line per round); replicas cut per-line fan-in to 32 and spread
//    load over 8x more LLC slices.
// Everything else identical to R0: S2 kept, sc0 sc1, single red[64],
// single-asm-block poll (issue+waitcnt+check in one block — R1/R3 proved
// split-asm register lifetimes corrupt data), W.x before poll.
//
// Parity-2 slot safety (per replica, reader-subset-invariant): block b
// overwrites pair[r][p][j] (h_t -> h_{t+2}) at step t+2 only after its
// poll of ALL h_{t+1} tags succeeded; any block publishes h_{t+1} only
// after consuming h_t. Tags monotonic per slot; poll uses >=.
// Workspace: 8*2*1024 u64 = 128 KB, zeroed.
//
// out rows 0..4094: written by rotating block (t & 255) as one coalesced
// 4 KB row straight from poll registers. Row 4095 + h_T + c_T: per-block
// lanes 0-3 at the final step.
// ---------------------------------------------------------------------------
__global__ __launch_bounds__(256, 1) void lstm_fused(
    const float* __restrict__ x,    // [4096,1024]
    const float* __restrict__ W,    // [1024,4096]
    const float* __restrict__ U,    // [1024,4096]
    const float* __restrict__ bias, // [4096]
    float* __restrict__ out,        // [4096*1024 + 1024 + 1024]
    unsigned long long* __restrict__ pairs) // [8][2][1024] {f32,u32}, zeroed
{
    const int tid  = threadIdx.x;
    const int b    = blockIdx.x;
    const int c    = tid & 15;
    const int s    = tid >> 4;
    const int col  = (c >> 2) * 1024 + b * 4 + (c & 3);
    const int lane = tid & 63;
    const int wave = tid >> 6;

    __shared__ __align__(16) float h_lds[16 * 68];     // h[k] at (k>>6)*68+(k&63)
    __shared__ __align__(16) float x_lds[2][16 * 68];
    __shared__ __align__(16) float red[64];
    __shared__ __align__(16) float bias_l[16];

    float Ureg[64], Wreg[64];
    #pragma unroll
    for (int i = 0; i < 64; ++i) {
        const size_t r = (size_t)(s * 64 + i) * 4096 + col;
        Ureg[i] = U[r];
        Wreg[i] = W[r];
    }
    if (tid < 16) bias_l[tid] = bias[col];

    for (int i = tid; i < 16 * 68; i += 256) h_lds[i] = 0.0f;   // h0 = 0
    const int xofs = (tid >> 4) * 68 + (tid & 15) * 4;
    *(f32x4*)&x_lds[0][xofs] = *(const f32x4*)(x + (size_t)tid * 4);
    f32x4 xpre = *(const f32x4*)(x + 1024 + (size_t)tid * 4);
    __syncthreads();

    const int hbase = s * 68;
    const int hofs  = ((tid * 4) >> 6) * 68 + ((tid * 4) & 63);  // stage slot

    // prologue: W.x_0 partial (4 independent FMA chains)
    float acc_x;
    {
        float b0 = 0.f, b1 = 0.f, b2 = 0.f, b3 = 0.f;
        #pragma unroll
        for (int i = 0; i < 16; ++i) {
            f32x4 x4 = *(const f32x4*)&x_lds[0][hbase + 4 * i];
            b0 += x4.x * Wreg[4*i];   b1 += x4.y * Wreg[4*i+1];
            b2 += x4.z * Wreg[4*i+2]; b3 += x4.w * Wreg[4*i+3];
        }
        acc_x = (b0 + b1) + (b2 + b3);
    }

    float c_reg = 0.0f;   // cell state: wave-0 lane u tracks unit b*4+(u&3)

    for (int t = 0; t < T_STEPS; ++t) {
        const int p   = t & 1;
        const int nxt = (t + 1) & 1;

        // 1: acc = W.x_t (precomputed) + U.h_{t-1}
        float acc;
        {
            float a0 = 0.f, a1 = 0.f, a2 = 0.f, a3 = 0.f;
            #pragma unroll
            for (int i = 0; i < 16; ++i) {
                f32x4 h4 = *(const f32x4*)&h_lds[hbase + 4 * i];
                a0 += h4.x * Ureg[4*i];   a1 += h4.y * Ureg[4*i+1];
                a2 += h4.z * Ureg[4*i+2]; a3 += h4.w * Ureg[4*i+3];
            }
            acc = acc_x + ((a0 + a1) + (a2 + a3));
        }
        // 2: lanes {c, c+16, c+32, c+48} share a column
        acc += __shfl_down(acc, 32);
        acc += __shfl_down(acc, 16);
        if (lane < 16) red[wave * 16 + lane] = acc;

        // rotate x double-buffer: write x_{t+1}, prefetch x_{t+2}
        *(f32x4*)&x_lds[nxt][xofs] = xpre;
        {
            const int tp2 = (t + 2 < T_STEPS) ? (t + 2) : (T_STEPS - 1);
            xpre = *(const f32x4*)(x + (size_t)tp2 * 1024 + tid * 4);
        }
        __syncthreads();   // [S1] red + x_lds[nxt] visible

        // 3: wave 0 — gates; lanes 0-31 publish {h, t+1} pairs, lane l ->
        //    unit b*4+(l&3) in replica l>>2 (one store instruction total)
        if (wave == 0) {
            const int cc = lane & 15;
            const float gv = red[cc] + red[16 + cc] + red[32 + cc] + red[48 + cc]
                           + bias_l[cc];
            const int u = lane & 3;
            const float gi = __shfl(gv, u);
            const float gf = __shfl(gv, 4 + u);
            const float gg = __shfl(gv, 8 + u);
            const float go = __shfl(gv, 12 + u);
            const float iv = 1.0f / (1.0f + __expf(-gi));
            const float fv = 1.0f / (1.0f + __expf(-gf));
            const float tg = 1.0f - 2.0f / (1.0f + __expf(2.0f * gg));
            const float ov = 1.0f / (1.0f + __expf(-go));
            const float cn = fv * c_reg + iv * tg;
            c_reg = cn;
            const float hn = ov * (1.0f - 2.0f / (1.0f + __expf(2.0f * cn)));
            if (t == T_STEPS - 1) {
                if (lane < 4) {
                    out[(size_t)t * HID + b * 4 + lane] = hn;               // row 4095
                    out[(size_t)T_STEPS * HID + b * 4 + lane] = hn;         // h_T
                    out[(size_t)T_STEPS * HID + HID + b * 4 + lane] = cn;   // c_T
                }
            } else if (lane < 32) {
                u32x2 pr;
                pr.x = f2u(hn);
                pr.y = (unsigned int)(t + 1);
                const int rep = lane >> 2;   // replica 0..7
                unsigned long long* pp = pairs + (size_t)rep * 2048
                                       + (size_t)p * 1024 + b * 4 + u;
                asm volatile("global_store_dwordx2 %0, %1, off sc0 sc1"
                             :: "v"(pp), "v"(pr) : "memory");
            }
        }
        if (t == T_STEPS - 1) break;

        // 4: all threads — W.x_{t+1} (local work first, then wait)
        {
            float b0 = 0.f, b1 = 0.f, b2 = 0.f, b3 = 0.f;
            #pragma unroll
            for (int i = 0; i < 16; ++i) {
                f32x4 x4 = *(const f32x4*)&x_lds[nxt][hbase + 4 * i];
                b0 += x4.x * Wreg[4*i];   b1 += x4.y * Wreg[4*i+1];
                b2 += x4.z * Wreg[4*i+2]; b3 += x4.w * Wreg[4*i+3];
            }
            acc_x = (b0 + b1) + (b2 + b3);
        }

        // 5: every thread polls its 4 pairs from replica (b & 7).
        //    ONE asm block per attempt (issue + vmcnt(0) + check), nothing
        //    in flight at exit.
        {
            const unsigned int want = (unsigned int)(t + 1);
            const unsigned long long* pp = pairs + (size_t)(b & 7) * 2048
                                         + (size_t)p * 1024 + tid * 4;
            u32x4 q0, q1;
            for (;;) {
                asm volatile("global_load_dwordx4 %0, %2, off sc0 sc1\n\t"
                             "global_load_dwordx4 %1, %3, off sc0 sc1\n\t"
                             "s_waitcnt vmcnt(0)"
                             : "=&v"(q0), "=&v"(q1)
                             : "v"(pp), "v"(pp + 2) : "memory");
                if (q0.y >= want && q0.w >= want && q1.y >= want && q1.w >= want)
                    break;
            }
            f32x4 hv4;
            hv4.x = u2f(q0.x); hv4.y = u2f(q0.z);
            hv4.z = u2f(q1.x); hv4.w = u2f(q1.z);
            // rotating writer: block (t & 255) emits the full coalesced row t
            if (b == (t & 255))
                *(f32x4*)(out + (size_t)t * HID + tid * 4) = hv4;
            *(f32x4*)&h_lds[hofs] = hv4;   // stage h_t
        }
        __syncthreads();   // [S2] h_t staged
    }
}

extern "C" void kernel_launch(void* const* d_in, const int* in_sizes, int n_in,
                              void* d_out, int out_size, void* d_ws, size_t ws_size,
                              hipStream_t stream) {
    const float* x    = (const float*)d_in[0];
    const float* W    = (const float*)d_in[1];
    const float* U    = (const float*)d_in[2];
    const float* bias = (const float*)d_in[3];
    float* out = (float*)d_out;

    // Workspace: pairs[8][2][1024] x 8 B = 128 KB @ +0 (zeroed: tag fields
    // must start below 1; re-poisoned 0xAA would read as huge tags).
    unsigned long long* pairs = (unsigned long long*)d_ws;

    hipMemsetAsync(pairs, 0, (size_t)NREP * 2 * 1024 * sizeof(unsigned long long), stream);
    lstm_fused<<<NBLK, 256, 0, stream>>>(x, W, U, bias, out, pairs);
}